// Round 1
// 3769.846 us; speedup vs baseline: 1.1221x; 1.1221x over previous
//
#include <hip/hip_runtime.h>
#include <math.h>

// ---------------- problem constants ----------------
#define N_AUTHOR 100000
#define N_FOS    30000
#define N_INST   8000
#define N_PAPER  150000
#define N_TOTAL  288000
#define NEDGE    500000
// row offsets in NODE_ORDER = [author, fos, inst, paper]
#define OFF_AUTHOR 0
#define OFF_FOS    100000
#define OFF_INST   130000
#define OFF_PAPER  138000
#define MAXN 150016   // padded max node count for int buffers

// ---------------- tiled SGEMM v2: C = A[N,256] @ B[256,M] (+bias) ----------------
// block 256 threads, tile 128 rows x BN cols, per-thread 8 x (BN/16).
// A staged TRANSPOSED As[kk][row] (pad 132) so fragment reads are ds_read_b128.
template<int BN, bool HAS_BIAS>
__launch_bounds__(256)
__global__ void sgemm_k256_v2(const float* __restrict__ A, const float* __restrict__ B,
                              const float* __restrict__ bias, float* __restrict__ C,
                              int N, int M) {
    constexpr int TN = BN / 16;          // cols per thread: 8 (BN=128) or 4 (BN=64)
    constexpr int C4 = BN / 4;           // float4 slots per Bs row
    __shared__ float As[16][132];        // [kk][row], padded: staging writes 2-way max
    __shared__ float Bs[16][BN];
    const int tid = threadIdx.x;
    const int tx = tid & 15, ty = tid >> 4;
    const int rowBase = blockIdx.x * 128;
    const int colBase = blockIdx.y * BN;

    float acc[8][TN];
#pragma unroll
    for (int i = 0; i < 8; ++i)
#pragma unroll
        for (int j = 0; j < TN; ++j) acc[i][j] = 0.0f;

    for (int k0 = 0; k0 < 256; k0 += 16) {
        // stage A transposed: 2 float4 per thread (128 rows x 16 k)
#pragma unroll
        for (int s = 0; s < 2; ++s) {
            int l = tid + s * 256;
            int row = l >> 2, kp = l & 3;
            int grow = rowBase + row;
            float4 v = make_float4(0.f, 0.f, 0.f, 0.f);
            if (grow < N)
                v = *(const float4*)(A + (size_t)grow * 256 + k0 + kp * 4);
            As[kp * 4 + 0][row] = v.x;
            As[kp * 4 + 1][row] = v.y;
            As[kp * 4 + 2][row] = v.z;
            As[kp * 4 + 3][row] = v.w;
        }
        // stage B: (16*BN)/1024 float4 per thread, coalesced rows
#pragma unroll
        for (int s = 0; s < (16 * BN) / 1024; ++s) {
            int l = tid + s * 256;
            int kk = l / C4, c4 = l % C4;
            *(float4*)&Bs[kk][c4 * 4] =
                *(const float4*)(B + (size_t)(k0 + kk) * M + colBase + c4 * 4);
        }
        __syncthreads();
#pragma unroll
        for (int kk = 0; kk < 16; ++kk) {
            float a[8], b[TN];
            *(float4*)&a[0] = *(const float4*)&As[kk][ty * 4];
            *(float4*)&a[4] = *(const float4*)&As[kk][64 + ty * 4];
            *(float4*)&b[0] = *(const float4*)&Bs[kk][tx * 4];
            if constexpr (TN == 8) {
                *(float4*)&b[4] = *(const float4*)&Bs[kk][64 + tx * 4];
            }
#pragma unroll
            for (int i = 0; i < 8; ++i)
#pragma unroll
                for (int j = 0; j < TN; ++j)
                    acc[i][j] += a[i] * b[j];
        }
        __syncthreads();
    }
    // epilogue: float4 stores
#pragma unroll
    for (int i = 0; i < 8; ++i) {
        int row = rowBase + ty * 4 + (i & 3) + (i >> 2) * 64;
        if (row < N) {
#pragma unroll
            for (int jg = 0; jg < TN / 4; ++jg) {
                int col = colBase + jg * 64 + tx * 4;
                float4 o;
                o.x = acc[i][jg * 4 + 0];
                o.y = acc[i][jg * 4 + 1];
                o.z = acc[i][jg * 4 + 2];
                o.w = acc[i][jg * 4 + 3];
                if (HAS_BIAS) {
                    o.x += bias[col + 0];
                    o.y += bias[col + 1];
                    o.z += bias[col + 2];
                    o.w += bias[col + 3];
                }
                *(float4*)(C + (size_t)row * M + col) = o;
            }
        }
    }
}

// ---------------- CSR build ----------------
__global__ void zero_cnt(int* __restrict__ cnt, int n) {
    int i = blockIdx.x * 256 + threadIdx.x;
    if (i < n) cnt[i] = 0;
}

__global__ void histogram(const int* __restrict__ dst, int* __restrict__ cnt, int ne) {
    int e = blockIdx.x * 256 + threadIdx.x;
    if (e < ne) atomicAdd(cnt + dst[e], 1);
}

// block-wise inclusive scan of cnt -> incl, blocksum[b] = block total
__global__ void scan1(const int* __restrict__ cnt, int* __restrict__ incl,
                      int* __restrict__ blocksum, int n) {
    __shared__ int s[256];
    int t = threadIdx.x;
    int i = blockIdx.x * 256 + t;
    int v = (i < n) ? cnt[i] : 0;
    s[t] = v;
    __syncthreads();
#pragma unroll
    for (int off = 1; off < 256; off <<= 1) {
        int add = (t >= off) ? s[t - off] : 0;
        __syncthreads();
        s[t] += add;
        __syncthreads();
    }
    if (i < n) incl[i] = s[t];
    if (t == 255) blocksum[blockIdx.x] = s[255];
}

// single block: exclusive scan of blocksum (nb <= 1024)
__global__ void scan2(int* __restrict__ blocksum, int nb) {
    __shared__ int s[1024];
    int t = threadIdx.x;
    int v = (t < nb) ? blocksum[t] : 0;
    s[t] = v;
    __syncthreads();
#pragma unroll
    for (int off = 1; off < 1024; off <<= 1) {
        int add = (t >= off) ? s[t - off] : 0;
        __syncthreads();
        s[t] += add;
        __syncthreads();
    }
    if (t < nb) blocksum[t] = s[t] - v;   // exclusive
}

// cursor[i] = exclusive prefix of cnt = incl[i] - cnt[i] + blockoff
__global__ void scan3(const int* __restrict__ cnt, const int* __restrict__ incl,
                      const int* __restrict__ blocksum, int* __restrict__ cursor, int n) {
    int i = blockIdx.x * 256 + threadIdx.x;
    if (i < n) cursor[i] = incl[i] - cnt[i] + blocksum[blockIdx.x];
}

// fill: srcidx[slot] = src[e], slot allocated via cursor atomic
__global__ void fill_csr(const int* __restrict__ src, const int* __restrict__ dst,
                         int* __restrict__ cursor, int* __restrict__ srcidx, int ne) {
    int e = blockIdx.x * 256 + threadIdx.x;
    if (e < ne) {
        int pos = atomicAdd(cursor + dst[e], 1);
        srcidx[pos] = src[e];
    }
}

// ---------------- gather + reduce + fused combine ----------------
// one 64-lane wave per destination node; 4 waves (4 nodes) per block.
// unrolled by 4 edges: 4 independent 1KB row loads in flight (latency hiding).
__global__ void gather_combine(const float* __restrict__ bases_src,
                               const int* __restrict__ srcidx,
                               const int* __restrict__ cursor,
                               const int* __restrict__ cnt,
                               const float* __restrict__ w,
                               float* __restrict__ out, int ndt) {
    __shared__ float lds[4][512];   // per wave: [0..255]=mean, [256..511]=max
    const int wv = threadIdx.x >> 6;
    const int lane = threadIdx.x & 63;
    const int node = blockIdx.x * 4 + wv;
    const bool active = node < ndt;

    if (active) {
        int deg = cnt[node];
        int start = cursor[node] - deg;
        float4 s = make_float4(0.f, 0.f, 0.f, 0.f);
        float4 m = make_float4(-INFINITY, -INFINITY, -INFINITY, -INFINITY);
        const float4* b4 = (const float4*)bases_src;
        int i = 0;
        for (; i + 4 <= deg; i += 4) {
            int s0 = srcidx[start + i + 0];
            int s1 = srcidx[start + i + 1];
            int s2 = srcidx[start + i + 2];
            int s3 = srcidx[start + i + 3];
            float4 v0 = b4[(size_t)s0 * 64 + lane];
            float4 v1 = b4[(size_t)s1 * 64 + lane];
            float4 v2 = b4[(size_t)s2 * 64 + lane];
            float4 v3 = b4[(size_t)s3 * 64 + lane];
            s.x += (v0.x + v1.x) + (v2.x + v3.x);
            s.y += (v0.y + v1.y) + (v2.y + v3.y);
            s.z += (v0.z + v1.z) + (v2.z + v3.z);
            s.w += (v0.w + v1.w) + (v2.w + v3.w);
            m.x = fmaxf(m.x, fmaxf(fmaxf(v0.x, v1.x), fmaxf(v2.x, v3.x)));
            m.y = fmaxf(m.y, fmaxf(fmaxf(v0.y, v1.y), fmaxf(v2.y, v3.y)));
            m.z = fmaxf(m.z, fmaxf(fmaxf(v0.z, v1.z), fmaxf(v2.z, v3.z)));
            m.w = fmaxf(m.w, fmaxf(fmaxf(v0.w, v1.w), fmaxf(v2.w, v3.w)));
        }
        for (; i < deg; ++i) {
            int sidx = srcidx[start + i];
            const float4 v = b4[(size_t)sidx * 64 + lane];
            s.x += v.x; s.y += v.y; s.z += v.z; s.w += v.w;
            m.x = fmaxf(m.x, v.x); m.y = fmaxf(m.y, v.y);
            m.z = fmaxf(m.z, v.z); m.w = fmaxf(m.w, v.w);
        }
        float inv = 1.0f / fmaxf((float)deg, 1.0f);
        float4 mean = make_float4(s.x * inv, s.y * inv, s.z * inv, s.w * inv);
        m.x = isfinite(m.x) ? m.x : 0.0f;
        m.y = isfinite(m.y) ? m.y : 0.0f;
        m.z = isfinite(m.z) ? m.z : 0.0f;
        m.w = isfinite(m.w) ? m.w : 0.0f;
        ((float4*)(lds[wv]))[lane] = mean;
        ((float4*)(lds[wv] + 256))[lane] = m;
    }
    __syncthreads();
    if (active) {
        const float* wr = w + (size_t)node * 128;
        float* outr = out + (size_t)node * 256;
#pragma unroll
        for (int j = 0; j < 4; ++j) {
            int col = j * 64 + lane;       // dch = lane&31 -> conflict-free LDS banks
            int h = col >> 5, dch = col & 31;
            const float* wh = wr + h * 16;
            float acc = 0.0f;
#pragma unroll
            for (int k = 0; k < 8; ++k) {
                acc += wh[k] * lds[wv][k * 32 + dch];             // mean part
                acc += wh[8 + k] * lds[wv][256 + k * 32 + dch];   // max part
            }
            outr[col] += acc;
        }
    }
}

// ---------------- root combine: out[n,h,d] = sum_k w[n,h*8+k] * bases[n,k*32+d] ----------------
__global__ void root_combine(const float* __restrict__ w, const float* __restrict__ bases,
                             float* __restrict__ out, int n) {
    size_t i = (size_t)blockIdx.x * 256 + threadIdx.x;
    size_t tot = (size_t)n * 256;
    if (i >= tot) return;
    int node = (int)(i >> 8);
    int col = (int)(i & 255);
    int h = col >> 5, dch = col & 31;
    const float* wr = w + (size_t)node * 64 + h * 8;
    const float* br = bases + (size_t)node * 256 + dch;
    float acc = 0.0f;
#pragma unroll
    for (int k = 0; k < 8; ++k) acc += wr[k] * br[k * 32];
    out[i] = acc;
}

// ---------------- host launcher ----------------
extern "C" void kernel_launch(void* const* d_in, const int* in_sizes, int n_in,
                              void* d_out, int out_size, void* d_ws, size_t ws_size,
                              hipStream_t stream) {
    (void)in_sizes; (void)n_in; (void)out_size; (void)ws_size;

    const float* xs[4]  = { (const float*)d_in[0], (const float*)d_in[1],
                            (const float*)d_in[2], (const float*)d_in[3] };
    const int   nn[4]   = { N_AUTHOR, N_FOS, N_INST, N_PAPER };
    const int   off[4]  = { OFF_AUTHOR, OFF_FOS, OFF_INST, OFF_PAPER };

    const float* W_bases = (const float*)d_in[18];

    // workspace layout
    float* bases   = (float*)d_ws;                          // N_TOTAL*256 f32
    float* wbuf    = bases + (size_t)N_TOTAL * 256;         // 150000*128 f32
    int*   cnt     = (int*)(wbuf + (size_t)N_PAPER * 128);  // MAXN
    int*   incl    = cnt + MAXN;                            // MAXN
    int*   cursor  = incl + MAXN;                           // MAXN
    int*   blocksum= cursor + MAXN;                         // 1024
    int*   srcidx  = blocksum + 1024;                       // NEDGE

    float* out = (float*)d_out;

    // 1. bases = x @ W_bases for each node type  (M=256, two 128-col tiles)
    for (int t = 0; t < 4; ++t) {
        dim3 grid((nn[t] + 127) / 128, 2);
        sgemm_k256_v2<128, false><<<grid, 256, 0, stream>>>(
            xs[t], W_bases, nullptr, bases + (size_t)off[t] * 256, nn[t], 256);
    }

    // 2. root path (initializes d_out)
    const int rootWi[4] = {33, 35, 37, 39};
    for (int t = 0; t < 4; ++t) {
        dim3 grid((nn[t] + 127) / 128, 1);
        sgemm_k256_v2<64, true><<<grid, 256, 0, stream>>>(
            xs[t], (const float*)d_in[rootWi[t]], (const float*)d_in[rootWi[t] + 1],
            wbuf, nn[t], 64);
        int nb = (int)(((size_t)nn[t] * 256 + 255) / 256);
        root_combine<<<nb, 256, 0, stream>>>(
            wbuf, bases + (size_t)off[t] * 256, out + (size_t)off[t] * 256, nn[t]);
    }

    // 3. relations: {src_in, dst_in, st, dt, relW_in}
    const int rel[7][5] = {
        {4, 5, 0, 2, 19},   // a_i: author -> inst
        {6, 7, 2, 0, 21},   // i_a: inst -> author
        {8, 9, 0, 3, 23},   // a_p: author -> paper
        {10, 11, 3, 0, 25}, // p_a: paper -> author
        {12, 13, 3, 3, 27}, // p_p: paper -> paper
        {14, 15, 3, 1, 29}, // p_f: paper -> fos
        {16, 17, 1, 3, 31}, // f_p: fos -> paper
    };
    const int eb = (NEDGE + 255) / 256;
    for (int r = 0; r < 7; ++r) {
        int st = rel[r][2], dt = rel[r][3];
        int ndt = nn[dt];
        const int* srcp = (const int*)d_in[rel[r][0]];
        const int* dstp = (const int*)d_in[rel[r][1]];
        int nb256 = (ndt + 255) / 256;

        // CSR build
        zero_cnt<<<nb256, 256, 0, stream>>>(cnt, ndt);
        histogram<<<eb, 256, 0, stream>>>(dstp, cnt, NEDGE);
        scan1<<<nb256, 256, 0, stream>>>(cnt, incl, blocksum, ndt);
        scan2<<<1, 1024, 0, stream>>>(blocksum, nb256);
        scan3<<<nb256, 256, 0, stream>>>(cnt, incl, blocksum, cursor, ndt);
        fill_csr<<<eb, 256, 0, stream>>>(srcp, dstp, cursor, srcidx, NEDGE);

        // w = x_dt @ relW + relb  (M=128)
        dim3 grid((ndt + 127) / 128, 1);
        sgemm_k256_v2<128, true><<<grid, 256, 0, stream>>>(
            xs[dt], (const float*)d_in[rel[r][4]], (const float*)d_in[rel[r][4] + 1],
            wbuf, ndt, 128);

        // gather + reduce + combine (fused)
        gather_combine<<<(ndt + 3) / 4, 256, 0, stream>>>(
            bases + (size_t)off[st] * 256, srcidx, cursor, cnt,
            wbuf, out + (size_t)off[dt] * 256, ndt);
    }
}

// Round 2
// 2895.096 us; speedup vs baseline: 1.4611x; 1.3021x over previous
//
#include <hip/hip_runtime.h>
#include <math.h>

// ---------------- problem constants ----------------
#define N_AUTHOR 100000
#define N_FOS    30000
#define N_INST   8000
#define N_PAPER  150000
#define N_TOTAL  288000
#define NEDGE    500000
// row offsets in NODE_ORDER = [author, fos, inst, paper]
#define OFF_AUTHOR 0
#define OFF_FOS    100000
#define OFF_INST   130000
#define OFF_PAPER  138000
#define MAXN 150016   // padded max node count for int buffers

typedef __attribute__((ext_vector_type(8))) short bf16x8;
typedef __attribute__((ext_vector_type(4))) float f32x4;

// split x into hi (truncated bf16) + lo (bf16 of remainder): x ~= hi + lo, err <= 2^-16 |x|
__device__ inline void split_bf16(float x, unsigned short& h, unsigned short& l) {
    unsigned int u = __float_as_uint(x);
    h = (unsigned short)(u >> 16);
    float hf = __uint_as_float(u & 0xFFFF0000u);
    float lf = x - hf;                       // exact in fp32
    l = (unsigned short)(__float_as_uint(lf) >> 16);
}

// ---------------- B pre-split: B[256][M] f32 -> Bt_hi[M][256], Bt_lo[M][256] bf16 ----------------
__global__ void prep_bt(const float* __restrict__ B, unsigned short* __restrict__ bth,
                        unsigned short* __restrict__ btl, int M) {
    int t = blockIdx.x * 256 + threadIdx.x;
    if (t >= M * 32) return;
    int col = t >> 5, kq = (t & 31) * 8;
    bf16x8 hv, lv;
#pragma unroll
    for (int i = 0; i < 8; ++i) {
        float x = B[(size_t)(kq + i) * M + col];
        unsigned short h, l;
        split_bf16(x, h, l);
        hv[i] = (short)h;
        lv[i] = (short)l;
    }
    *(bf16x8*)(bth + (size_t)col * 256 + kq) = hv;
    *(bf16x8*)(btl + (size_t)col * 256 + kq) = lv;
}

// ---------------- split-bf16 MFMA GEMM: C = A[N,256] @ B[256,M] (+bias) ----------------
// block 256 threads = 4 waves (2x2), tile 128 x BN. wave tile 64 x BN/2.
// A staged hi/lo in LDS [row][k] pad-40; B-frags direct from pre-split global (L2-resident).
// mfma_f32_16x16x32_bf16: A row=lane&15,k=(lane>>4)*8+i ; B col=lane&15,same k ;
// C/D col=lane&15, row=(lane>>4)*4+reg  [HW-verified layout]
template<int BN, bool HAS_BIAS>
__launch_bounds__(256)
__global__ void mfma_gemm(const float* __restrict__ A, const unsigned short* __restrict__ bth,
                          const unsigned short* __restrict__ btl, const float* __restrict__ bias,
                          float* __restrict__ C, int N, int M) {
    constexpr int NT = BN / 32;            // 16-col tiles per wave: 4 (BN=128) or 2 (BN=64)
    __shared__ unsigned short Ah[128 * 40];
    __shared__ unsigned short Al[128 * 40];
    const int tid = threadIdx.x;
    const int lane = tid & 63;
    const int wv = tid >> 6;
    const int wr = wv >> 1, wc = wv & 1;
    const int rowBase = blockIdx.x * 128;
    const int colBase = blockIdx.y * BN;

    // staging assignment: 2 threads per row, 16 f32 each
    const int srow = tid >> 1;
    const int skh  = (tid & 1) * 16;
    const bool srowOK = (rowBase + srow) < N;
    const float* aptr = A + (size_t)(rowBase + srow) * 256 + skh;

    // fragment addressing
    const int fr = lane & 15;              // row/col within 16x16 tile
    const int fq = lane >> 4;              // k-quarter (8 elems each)
    const int arow0 = wr * 64 + fr;
    const int bcol0 = colBase + wc * (BN / 2) + fr;

    f32x4 acc[4][NT];
#pragma unroll
    for (int i = 0; i < 4; ++i)
#pragma unroll
        for (int j = 0; j < NT; ++j)
#pragma unroll
            for (int r = 0; r < 4; ++r) acc[i][j][r] = 0.0f;

    // prefetch first A block (k0 = 0)
    float4 av[4];
#pragma unroll
    for (int q = 0; q < 4; ++q)
        av[q] = srowOK ? *(const float4*)(aptr + q * 4) : make_float4(0.f, 0.f, 0.f, 0.f);

    for (int k0 = 0; k0 < 256; k0 += 32) {
        // B-frags for this k-step (global, tiny + L2-resident)
        bf16x8 bh[NT], bl[NT];
#pragma unroll
        for (int nt = 0; nt < NT; ++nt) {
            size_t boff = (size_t)(bcol0 + nt * 16) * 256 + k0 + fq * 8;
            bh[nt] = *(const bf16x8*)(bth + boff);
            bl[nt] = *(const bf16x8*)(btl + boff);
        }
        __syncthreads();                   // previous compute done -> safe to overwrite LDS
        // convert staged A regs -> hi/lo LDS
        const float* fv = (const float*)&av[0];
#pragma unroll
        for (int g = 0; g < 2; ++g) {
            bf16x8 hv, lv;
#pragma unroll
            for (int i = 0; i < 8; ++i) {
                unsigned short h, l;
                split_bf16(fv[g * 8 + i], h, l);
                hv[i] = (short)h;
                lv[i] = (short)l;
            }
            int waddr = srow * 40 + skh + g * 8;
            *(bf16x8*)(Ah + waddr) = hv;
            *(bf16x8*)(Al + waddr) = lv;
        }
        __syncthreads();
        // prefetch next A block (hidden under MFMAs below)
        if (k0 + 32 < 256) {
#pragma unroll
            for (int q = 0; q < 4; ++q)
                av[q] = srowOK ? *(const float4*)(aptr + k0 + 32 + q * 4)
                               : make_float4(0.f, 0.f, 0.f, 0.f);
        }
        // A-frags from LDS
        bf16x8 ah[4], alo[4];
#pragma unroll
        for (int mt = 0; mt < 4; ++mt) {
            int raddr = (arow0 + mt * 16) * 40 + fq * 8;
            ah[mt]  = *(const bf16x8*)(Ah + raddr);
            alo[mt] = *(const bf16x8*)(Al + raddr);
        }
        // 3-product split MFMA
#pragma unroll
        for (int mt = 0; mt < 4; ++mt)
#pragma unroll
            for (int nt = 0; nt < NT; ++nt) {
                acc[mt][nt] = __builtin_amdgcn_mfma_f32_16x16x32_bf16(ah[mt],  bh[nt], acc[mt][nt], 0, 0, 0);
                acc[mt][nt] = __builtin_amdgcn_mfma_f32_16x16x32_bf16(ah[mt],  bl[nt], acc[mt][nt], 0, 0, 0);
                acc[mt][nt] = __builtin_amdgcn_mfma_f32_16x16x32_bf16(alo[mt], bh[nt], acc[mt][nt], 0, 0, 0);
            }
    }

    // epilogue
#pragma unroll
    for (int mt = 0; mt < 4; ++mt) {
        int rb = rowBase + wr * 64 + mt * 16 + fq * 4;
#pragma unroll
        for (int nt = 0; nt < NT; ++nt) {
            int col = bcol0 + nt * 16;
            float bv = HAS_BIAS ? bias[col] : 0.0f;
#pragma unroll
            for (int r = 0; r < 4; ++r) {
                int row = rb + r;
                if (row < N) C[(size_t)row * M + col] = acc[mt][nt][r] + bv;
            }
        }
    }
}

// ---------------- CSR build ----------------
__global__ void zero_cnt(int* __restrict__ cnt, int n) {
    int i = blockIdx.x * 256 + threadIdx.x;
    if (i < n) cnt[i] = 0;
}

__global__ void histogram(const int* __restrict__ dst, int* __restrict__ cnt, int ne) {
    int e = blockIdx.x * 256 + threadIdx.x;
    if (e < ne) atomicAdd(cnt + dst[e], 1);
}

__global__ void scan1(const int* __restrict__ cnt, int* __restrict__ incl,
                      int* __restrict__ blocksum, int n) {
    __shared__ int s[256];
    int t = threadIdx.x;
    int i = blockIdx.x * 256 + t;
    int v = (i < n) ? cnt[i] : 0;
    s[t] = v;
    __syncthreads();
#pragma unroll
    for (int off = 1; off < 256; off <<= 1) {
        int add = (t >= off) ? s[t - off] : 0;
        __syncthreads();
        s[t] += add;
        __syncthreads();
    }
    if (i < n) incl[i] = s[t];
    if (t == 255) blocksum[blockIdx.x] = s[255];
}

__global__ void scan2(int* __restrict__ blocksum, int nb) {
    __shared__ int s[1024];
    int t = threadIdx.x;
    int v = (t < nb) ? blocksum[t] : 0;
    s[t] = v;
    __syncthreads();
#pragma unroll
    for (int off = 1; off < 1024; off <<= 1) {
        int add = (t >= off) ? s[t - off] : 0;
        __syncthreads();
        s[t] += add;
        __syncthreads();
    }
    if (t < nb) blocksum[t] = s[t] - v;   // exclusive
}

__global__ void scan3(const int* __restrict__ cnt, const int* __restrict__ incl,
                      const int* __restrict__ blocksum, int* __restrict__ cursor, int n) {
    int i = blockIdx.x * 256 + threadIdx.x;
    if (i < n) cursor[i] = incl[i] - cnt[i] + blocksum[blockIdx.x];
}

__global__ void fill_csr(const int* __restrict__ src, const int* __restrict__ dst,
                         int* __restrict__ cursor, int* __restrict__ srcidx, int ne) {
    int e = blockIdx.x * 256 + threadIdx.x;
    if (e < ne) {
        int pos = atomicAdd(cursor + dst[e], 1);
        srcidx[pos] = src[e];
    }
}

// ---------------- gather + reduce + fused combine ----------------
__global__ void gather_combine(const float* __restrict__ bases_src,
                               const int* __restrict__ srcidx,
                               const int* __restrict__ cursor,
                               const int* __restrict__ cnt,
                               const float* __restrict__ w,
                               float* __restrict__ out, int ndt) {
    __shared__ float lds[4][512];   // per wave: [0..255]=mean, [256..511]=max
    const int wv = threadIdx.x >> 6;
    const int lane = threadIdx.x & 63;
    const int node = blockIdx.x * 4 + wv;
    const bool active = node < ndt;

    if (active) {
        int deg = cnt[node];
        int start = cursor[node] - deg;
        float4 s = make_float4(0.f, 0.f, 0.f, 0.f);
        float4 m = make_float4(-INFINITY, -INFINITY, -INFINITY, -INFINITY);
        const float4* b4 = (const float4*)bases_src;
        int i = 0;
        for (; i + 4 <= deg; i += 4) {
            int s0 = srcidx[start + i + 0];
            int s1 = srcidx[start + i + 1];
            int s2 = srcidx[start + i + 2];
            int s3 = srcidx[start + i + 3];
            float4 v0 = b4[(size_t)s0 * 64 + lane];
            float4 v1 = b4[(size_t)s1 * 64 + lane];
            float4 v2 = b4[(size_t)s2 * 64 + lane];
            float4 v3 = b4[(size_t)s3 * 64 + lane];
            s.x += (v0.x + v1.x) + (v2.x + v3.x);
            s.y += (v0.y + v1.y) + (v2.y + v3.y);
            s.z += (v0.z + v1.z) + (v2.z + v3.z);
            s.w += (v0.w + v1.w) + (v2.w + v3.w);
            m.x = fmaxf(m.x, fmaxf(fmaxf(v0.x, v1.x), fmaxf(v2.x, v3.x)));
            m.y = fmaxf(m.y, fmaxf(fmaxf(v0.y, v1.y), fmaxf(v2.y, v3.y)));
            m.z = fmaxf(m.z, fmaxf(fmaxf(v0.z, v1.z), fmaxf(v2.z, v3.z)));
            m.w = fmaxf(m.w, fmaxf(fmaxf(v0.w, v1.w), fmaxf(v2.w, v3.w)));
        }
        for (; i < deg; ++i) {
            int sidx = srcidx[start + i];
            const float4 v = b4[(size_t)sidx * 64 + lane];
            s.x += v.x; s.y += v.y; s.z += v.z; s.w += v.w;
            m.x = fmaxf(m.x, v.x); m.y = fmaxf(m.y, v.y);
            m.z = fmaxf(m.z, v.z); m.w = fmaxf(m.w, v.w);
        }
        float inv = 1.0f / fmaxf((float)deg, 1.0f);
        float4 mean = make_float4(s.x * inv, s.y * inv, s.z * inv, s.w * inv);
        m.x = isfinite(m.x) ? m.x : 0.0f;
        m.y = isfinite(m.y) ? m.y : 0.0f;
        m.z = isfinite(m.z) ? m.z : 0.0f;
        m.w = isfinite(m.w) ? m.w : 0.0f;
        ((float4*)(lds[wv]))[lane] = mean;
        ((float4*)(lds[wv] + 256))[lane] = m;
    }
    __syncthreads();
    if (active) {
        const float* wr = w + (size_t)node * 128;
        float* outr = out + (size_t)node * 256;
#pragma unroll
        for (int j = 0; j < 4; ++j) {
            int col = j * 64 + lane;       // dch = lane&31 -> conflict-free LDS banks
            int h = col >> 5, dch = col & 31;
            const float* wh = wr + h * 16;
            float acc = 0.0f;
#pragma unroll
            for (int k = 0; k < 8; ++k) {
                acc += wh[k] * lds[wv][k * 32 + dch];             // mean part
                acc += wh[8 + k] * lds[wv][256 + k * 32 + dch];   // max part
            }
            outr[col] += acc;
        }
    }
}

// ---------------- root combine ----------------
__global__ void root_combine(const float* __restrict__ w, const float* __restrict__ bases,
                             float* __restrict__ out, int n) {
    size_t i = (size_t)blockIdx.x * 256 + threadIdx.x;
    size_t tot = (size_t)n * 256;
    if (i >= tot) return;
    int node = (int)(i >> 8);
    int col = (int)(i & 255);
    int h = col >> 5, dch = col & 31;
    const float* wr = w + (size_t)node * 64 + h * 8;
    const float* br = bases + (size_t)node * 256 + dch;
    float acc = 0.0f;
#pragma unroll
    for (int k = 0; k < 8; ++k) acc += wr[k] * br[k * 32];
    out[i] = acc;
}

// ---------------- host launcher ----------------
extern "C" void kernel_launch(void* const* d_in, const int* in_sizes, int n_in,
                              void* d_out, int out_size, void* d_ws, size_t ws_size,
                              hipStream_t stream) {
    (void)in_sizes; (void)n_in; (void)out_size; (void)ws_size;

    const float* xs[4]  = { (const float*)d_in[0], (const float*)d_in[1],
                            (const float*)d_in[2], (const float*)d_in[3] };
    const int   nn[4]   = { N_AUTHOR, N_FOS, N_INST, N_PAPER };
    const int   off[4]  = { OFF_AUTHOR, OFF_FOS, OFF_INST, OFF_PAPER };

    const float* W_bases = (const float*)d_in[18];

    // workspace layout
    float* bases   = (float*)d_ws;                          // N_TOTAL*256 f32
    float* wbuf    = bases + (size_t)N_TOTAL * 256;         // 150000*128 f32
    int*   cnt     = (int*)(wbuf + (size_t)N_PAPER * 128);  // MAXN
    int*   incl    = cnt + MAXN;                            // MAXN (reused as Bt scratch when dead)
    int*   cursor  = incl + MAXN;                           // MAXN
    int*   blocksum= cursor + MAXN;                         // 1024
    int*   srcidx  = blocksum + 1024;                       // NEDGE

    float* out = (float*)d_out;

    // Bt scratch lives in incl (600KB >= 256KB needed for M=256); incl is only
    // live between scan1 and scan3 of each relation, and Bt use never overlaps that.
    unsigned short* bth = (unsigned short*)incl;

    // 1. bases = x @ W_bases (M=256): pre-split W once, reuse for all 4 types
    {
        unsigned short* btl = bth + (size_t)256 * 256;
        prep_bt<<<32, 256, 0, stream>>>(W_bases, bth, btl, 256);
        for (int t = 0; t < 4; ++t) {
            dim3 grid((nn[t] + 127) / 128, 2);
            mfma_gemm<128, false><<<grid, 256, 0, stream>>>(
                xs[t], bth, btl, nullptr, bases + (size_t)off[t] * 256, nn[t], 256);
        }
    }

    // 2. root path (initializes d_out)
    const int rootWi[4] = {33, 35, 37, 39};
    for (int t = 0; t < 4; ++t) {
        unsigned short* btl = bth + (size_t)64 * 256;
        prep_bt<<<8, 256, 0, stream>>>((const float*)d_in[rootWi[t]], bth, btl, 64);
        dim3 grid((nn[t] + 127) / 128, 1);
        mfma_gemm<64, true><<<grid, 256, 0, stream>>>(
            xs[t], bth, btl, (const float*)d_in[rootWi[t] + 1], wbuf, nn[t], 64);
        int nb = (int)(((size_t)nn[t] * 256 + 255) / 256);
        root_combine<<<nb, 256, 0, stream>>>(
            wbuf, bases + (size_t)off[t] * 256, out + (size_t)off[t] * 256, nn[t]);
    }

    // 3. relations: {src_in, dst_in, st, dt, relW_in}
    const int rel[7][5] = {
        {4, 5, 0, 2, 19},   // a_i: author -> inst
        {6, 7, 2, 0, 21},   // i_a: inst -> author
        {8, 9, 0, 3, 23},   // a_p: author -> paper
        {10, 11, 3, 0, 25}, // p_a: paper -> author
        {12, 13, 3, 3, 27}, // p_p: paper -> paper
        {14, 15, 3, 1, 29}, // p_f: paper -> fos
        {16, 17, 1, 3, 31}, // f_p: fos -> paper
    };
    const int eb = (NEDGE + 255) / 256;
    for (int r = 0; r < 7; ++r) {
        int st = rel[r][2], dt = rel[r][3];
        int ndt = nn[dt];
        const int* srcp = (const int*)d_in[rel[r][0]];
        const int* dstp = (const int*)d_in[rel[r][1]];
        int nb256 = (ndt + 255) / 256;

        // CSR build (uses incl; must precede prep_bt's reuse of that region)
        zero_cnt<<<nb256, 256, 0, stream>>>(cnt, ndt);
        histogram<<<eb, 256, 0, stream>>>(dstp, cnt, NEDGE);
        scan1<<<nb256, 256, 0, stream>>>(cnt, incl, blocksum, ndt);
        scan2<<<1, 1024, 0, stream>>>(blocksum, nb256);
        scan3<<<nb256, 256, 0, stream>>>(cnt, incl, blocksum, cursor, ndt);
        fill_csr<<<eb, 256, 0, stream>>>(srcp, dstp, cursor, srcidx, NEDGE);

        // w = x_dt @ relW + relb  (M=128), split-bf16 MFMA
        unsigned short* btl = bth + (size_t)128 * 256;
        prep_bt<<<16, 256, 0, stream>>>((const float*)d_in[rel[r][4]], bth, btl, 128);
        dim3 grid((ndt + 127) / 128, 1);
        mfma_gemm<128, true><<<grid, 256, 0, stream>>>(
            xs[dt], bth, btl, (const float*)d_in[rel[r][4] + 1], wbuf, ndt, 128);

        // gather + reduce + combine (fused)
        gather_combine<<<(ndt + 3) / 4, 256, 0, stream>>>(
            bases + (size_t)off[st] * 256, srcidx, cursor, cnt,
            wbuf, out + (size_t)off[dt] * 256, ndt);
    }
}